// Round 6
// baseline (90.860 us; speedup 1.0000x reference)
//
#include <hip/hip_runtime.h>
#include <math.h>

// ---- reference constants ----
#define NSTEPSV  50
#define NSLICE   8        // proven: rate<=10 -> each full dev step burns >=2.0s
                          // of the 15s budget -> <=8 z-slices ever consulted
#define KTAB     8192     // table resolution (verified absmax 1.0 at R2/R3/R4)
#define NBUILD   257      // builder blocks: 32 samples x 8 slices = 256 thr each
#define NLOOK    512      // consumer blocks: 256 thr x 4 px = 524288 px
#define MAGICF   0x5A17C0DEu   // != 0xAAAAAAAA poison -> cannot be spoofed

static constexpr float F_DZ      = 1000.0f / 50.0f;   // dz = 20
static constexpr float F_RMIN    = 0.8f;
static constexpr float F_RMAX    = 10.0f;
static constexpr float F_DEVT    = 15.0f;
static constexpr float F_AMACK   = 1.4264850748500002f;  // 0.99^5 * 6/4
static constexpr double D_LOG2E  = 1.4426950408889634;
static constexpr float F_K0      = (float)(-0.1 * D_LOG2E);      // lat step
static constexpr float F_KA      = (float)(-0.00075 * D_LOG2E);  // bulk: A term
static constexpr float F_KB      = (float)(-0.00005 * D_LOG2E);  // bulk: B term
static constexpr float F_KA0     = (float)(-0.0005 * D_LOG2E);   // initial bulk

#if __has_builtin(__builtin_amdgcn_exp2f)
#define EXP2F(x) __builtin_amdgcn_exp2f(x)
#else
#define EXP2F(x) exp2f(x)
#endif

#if __has_builtin(__builtin_amdgcn_fence)
#define ACQUIRE_FENCE() __builtin_amdgcn_fence(__ATOMIC_ACQUIRE, "agent")
#else
#define ACQUIRE_FENCE() __threadfence()
#endif

// One z-slice's Mack development rate for intensity I (identical arithmetic
// to the round-1..4 verified kernels).
__device__ __forceinline__ float slice_rate(float I, int slice) {
    const float z  = (float)((double)slice * (1000.0 / 49.0));  // linspace(0,1000,50)
    const float cB = I * EXP2F(F_KB * z);
    const float k1 = F_KA * z;
    float bulk = I * EXP2F(F_KA0 * z);
    float lat  = 1.0f;
    #pragma unroll
    for (int s = 0; s < NSTEPSV - 1; ++s) {
        lat  *= EXP2F(F_K0 * bulk);
        bulk  = cB * EXP2F(k1 * lat);
    }
    lat *= EXP2F(F_K0 * bulk);                   // final step (bulk update dead)
    const float om  = 1.0f - lat;
    const float om2 = om * om;
    const float pm  = om2 * om2 * om;            // (1-lat)^5
    float rate = (F_AMACK + 1.0f) * pm / (F_AMACK + pm) * F_RMAX + F_RMIN;
    return fminf(fmaxf(rate, F_RMIN), F_RMAX);
}

__device__ __forceinline__ float dev_depth(const float* r8) {
    float t = F_DEVT, res = 0.0f;
    #pragma unroll
    for (int iz = 0; iz < NSLICE; ++iz) {
        const float r   = r8[iz];
        const float cur = r * t;
        if (cur <= F_DZ) { res += cur; break; }
        res += F_DZ;
        t   -= F_DZ / r;
    }
    return res;
}

// Fused build+lookup, one dispatch. 769 blocks x 256 thr; __launch_bounds__
// (256,4) caps VGPR at 128 (actual ~32) => >=4 blocks/CU => 1024 co-resident
// capacity >= 769: builders always execute regardless of dispatch order.
// Spin-cost lessons from R3: only wave 0 polls, RELAXED loads, s_sleep
// throttle, single acquire fence after exit.
__global__ __launch_bounds__(256, 4) void fused_kernel(const float* __restrict__ img,
                                                       float* __restrict__ out,
                                                       float* __restrict__ T,
                                                       unsigned* __restrict__ flags) {
    const int b = blockIdx.x;
    const int t = threadIdx.x;
    __shared__ float rates[32][NSLICE + 1];      // builder phase only; +1 pad

    if (b < NBUILD) {
        // ---- builder: 32 samples x 8 slices, one (sample,slice) per thread ----
        const int ls     = t >> 3;
        const int slice  = t & 7;
        const int sample = b * 32 + ls;
        if (sample <= KTAB)
            rates[ls][slice] = slice_rate((float)sample * (1.0f / (float)KTAB), slice);
        __syncthreads();
        if (t < 32) {
            const int s2 = b * 32 + t;
            if (s2 <= KTAB) T[s2] = dev_depth(rates[t]);
        }
        // publish: drain stores, device fence, then release flag.
        __syncthreads();
        __threadfence();
        if (t == 0)
            __hip_atomic_store(&flags[b], MAGICF, __ATOMIC_RELEASE,
                               __HIP_MEMORY_SCOPE_AGENT);
        return;
    }

    // ---- consumer: 4 px per thread, float4 in/out ----
    const int g = (b - NBUILD) * 256 + t;
    const float4 v = ((const float4*)img)[g];    // issue loads BEFORE spinning

    float x[4] = {v.x, v.y, v.z, v.w};
    int   j[4];
    float f[4];
    #pragma unroll
    for (int k = 0; k < 4; ++k) {
        const float xf = x[k] * (float)KTAB;     // I in [0,1) -> [0,KTAB)
        int jj = (int)xf;
        jj = jj < 0 ? 0 : (jj > KTAB - 1 ? KTAB - 1 : jj);
        j[k] = jj;
        f[k] = xf - (float)jj;
    }

    // wave 0 polls all 257 flags (5 per lane), relaxed + sleep-throttled.
    if (t < 64) {
        for (;;) {
            bool ok = true;
            #pragma unroll
            for (int k = 0; k < 5; ++k) {
                const int fi = t + 64 * k;
                if (fi < NBUILD)
                    ok &= (__hip_atomic_load(&flags[fi], __ATOMIC_RELAXED,
                                             __HIP_MEMORY_SCOPE_AGENT) == MAGICF);
            }
            if (__all(ok)) break;
            __builtin_amdgcn_s_sleep(16);        // ~1024 cyc between rounds
        }
    }
    __syncthreads();                             // other waves park at barrier
    ACQUIRE_FENCE();                             // make builders' T stores visible

    float4 o;
    float* op = &o.x;
    #pragma unroll
    for (int k = 0; k < 4; ++k) {
        const float t0 = T[j[k]];
        const float t1 = T[j[k] + 1];
        op[k] = fmaf(f[k], t1 - t0, t0);
    }
    ((float4*)out)[g] = o;
}

// Fallback: direct per-pixel simulation (round-1 verified).
__global__ __launch_bounds__(256) void resist_direct(const float* __restrict__ img,
                                                     float* __restrict__ out, int n) {
    int idx = blockIdx.x * blockDim.x + threadIdx.x;
    if (idx >= n) return;
    const float I = img[idx];
    float r8[NSLICE];
    #pragma unroll
    for (int iz = 0; iz < NSLICE; ++iz) r8[iz] = slice_rate(I, iz);
    out[idx] = dev_depth(r8);
}

extern "C" void kernel_launch(void* const* d_in, const int* in_sizes, int n_in,
                              void* d_out, int out_size, void* d_ws, size_t ws_size,
                              hipStream_t stream) {
    const float* img = (const float*)d_in[0];
    float* out = (float*)d_out;
    const int n = in_sizes[0];                   // 2*512*512 = 524288

    const size_t flags_off = 33024;              // past 32772B table, 128B-aligned
    const size_t need      = flags_off + NBUILD * sizeof(unsigned);

    if (ws_size >= need && n == NLOOK * 256 * 4) {
        float*    T     = (float*)d_ws;
        unsigned* flags = (unsigned*)((char*)d_ws + flags_off);
        fused_kernel<<<NBUILD + NLOOK, 256, 0, stream>>>(img, out, T, flags);
    } else {
        resist_direct<<<(n + 255) / 256, 256, 0, stream>>>(img, out, n);
    }
}

// Round 7
// 56.915 us; speedup vs baseline: 1.5964x; 1.5964x over previous
//
#include <hip/hip_runtime.h>
#include <math.h>

// ---- reference constants ----
#define NSTEPSV  50
#define NSLICE   8        // proven: rate<=10 -> each full dev step burns >=2.0s
                          // of the 15s budget -> <=8 z-slices ever consulted
#define KTAB     8192     // table resolution (verified absmax 1.0 at R2..R6)
#define NBUILD   257      // build blocks: 32 samples x 8 slices = 256 thr each
#define NLOOK    512      // lookup blocks: 256 thr x 4 px = 524288 px

static constexpr float F_DZ      = 1000.0f / 50.0f;   // dz = 20
static constexpr float F_RMIN    = 0.8f;
static constexpr float F_RMAX    = 10.0f;
static constexpr float F_DEVT    = 15.0f;
static constexpr float F_AMACK   = 1.4264850748500002f;  // 0.99^5 * 6/4
static constexpr double D_LOG2E  = 1.4426950408889634;
static constexpr float F_K0      = (float)(-0.1 * D_LOG2E);      // lat step
static constexpr float F_KA      = (float)(-0.00075 * D_LOG2E);  // bulk: A term
static constexpr float F_KB      = (float)(-0.00005 * D_LOG2E);  // bulk: B term
static constexpr float F_KA0     = (float)(-0.0005 * D_LOG2E);   // initial bulk

#if __has_builtin(__builtin_amdgcn_exp2f)
#define EXP2F(x) __builtin_amdgcn_exp2f(x)
#else
#define EXP2F(x) exp2f(x)
#endif

// One z-slice's Mack development rate for intensity I (identical arithmetic
// to the round-1..4 verified kernels).
__device__ __forceinline__ float slice_rate(float I, int slice) {
    const float z  = (float)((double)slice * (1000.0 / 49.0));  // linspace(0,1000,50)
    const float cB = I * EXP2F(F_KB * z);
    const float k1 = F_KA * z;
    float bulk = I * EXP2F(F_KA0 * z);
    float lat  = 1.0f;
    #pragma unroll
    for (int s = 0; s < NSTEPSV - 1; ++s) {
        lat  *= EXP2F(F_K0 * bulk);
        bulk  = cB * EXP2F(k1 * lat);
    }
    lat *= EXP2F(F_K0 * bulk);                   // final step (bulk update dead)
    const float om  = 1.0f - lat;
    const float om2 = om * om;
    const float pm  = om2 * om2 * om;            // (1-lat)^5
    float rate = (F_AMACK + 1.0f) * pm / (F_AMACK + pm) * F_RMAX + F_RMIN;
    return fminf(fmaxf(rate, F_RMIN), F_RMAX);
}

__device__ __forceinline__ float dev_depth(const float* r8) {
    float t = F_DEVT, res = 0.0f;
    #pragma unroll
    for (int iz = 0; iz < NSLICE; ++iz) {
        const float r   = r8[iz];
        const float cur = r * t;
        if (cur <= F_DZ) { res += cur; break; }
        res += F_DZ;
        t   -= F_DZ / r;
    }
    return res;
}

// Slice-parallel table build: one thread per (sample, slice).
// 257 blocks x 256 threads; dependent chain ~300 ops (~0.7us), real TLP.
// NOTE (R3/R6 lesson): do NOT fuse this with the lookup via intra-kernel
// flag handshakes — two independent spin designs cost 42-88us (stale-L1 /
// acquire-invalidate storms) vs the ~2us launch gap they save.
__global__ __launch_bounds__(256) void build_table_par(float* __restrict__ T) {
    const int b  = blockIdx.x;
    const int t  = threadIdx.x;
    __shared__ float rates[32][NSLICE + 1];      // +1 pad vs bank conflicts

    const int ls     = t >> 3;                   // local sample 0..31
    const int slice  = t & 7;                    // z-slice 0..7
    const int sample = b * 32 + ls;
    if (sample <= KTAB)
        rates[ls][slice] = slice_rate((float)sample * (1.0f / (float)KTAB), slice);
    __syncthreads();
    if (t < 32) {
        const int s2 = b * 32 + t;
        if (s2 <= KTAB) T[s2] = dev_depth(rates[t]);
    }
}

__global__ __launch_bounds__(256) void lookup4(const float* __restrict__ img,
                                               const float* __restrict__ T,
                                               float* __restrict__ out) {
    const int g = blockIdx.x * 256 + threadIdx.x;
    const float4 v = ((const float4*)img)[g];
    float x[4] = {v.x, v.y, v.z, v.w};
    float4 o;
    float* op = &o.x;
    #pragma unroll
    for (int k = 0; k < 4; ++k) {
        const float xf = x[k] * (float)KTAB;     // I in [0,1) -> [0,KTAB)
        int j = (int)xf;
        j = j < 0 ? 0 : (j > KTAB - 1 ? KTAB - 1 : j);
        const float f  = xf - (float)j;
        const float t0 = T[j];
        const float t1 = T[j + 1];
        op[k] = fmaf(f, t1 - t0, t0);
    }
    ((float4*)out)[g] = o;
}

// Fallback: direct per-pixel simulation (round-1 verified).
__global__ __launch_bounds__(256) void resist_direct(const float* __restrict__ img,
                                                     float* __restrict__ out, int n) {
    int idx = blockIdx.x * blockDim.x + threadIdx.x;
    if (idx >= n) return;
    const float I = img[idx];
    float r8[NSLICE];
    #pragma unroll
    for (int iz = 0; iz < NSLICE; ++iz) r8[iz] = slice_rate(I, iz);
    out[idx] = dev_depth(r8);
}

extern "C" void kernel_launch(void* const* d_in, const int* in_sizes, int n_in,
                              void* d_out, int out_size, void* d_ws, size_t ws_size,
                              hipStream_t stream) {
    const float* img = (const float*)d_in[0];
    float* out = (float*)d_out;
    const int n = in_sizes[0];                   // 2*512*512 = 524288

    const size_t tab_bytes = (size_t)(KTAB + 1) * sizeof(float);

    if (ws_size >= tab_bytes && n == NLOOK * 256 * 4) {
        float* T = (float*)d_ws;
        build_table_par<<<NBUILD, 256, 0, stream>>>(T);
        lookup4<<<NLOOK, 256, 0, stream>>>(img, T, out);
    } else {
        resist_direct<<<(n + 255) / 256, 256, 0, stream>>>(img, out, n);
    }
}